// Round 17
// baseline (1986.600 us; speedup 1.0000x reference)
//
#include <hip/hip_runtime.h>
#include <stdint.h>

#define Tsz 512
#define Dsz 256

// per-row prog[] indices: two fully independent single-row pipelines
#define P_VAN(row) ((row) * 7 + 0)
#define P_L1A(row) ((row) * 7 + 1)
#define P_L1B(row) ((row) * 7 + 2)
#define P_L2A(row) ((row) * 7 + 3)
#define P_L2B(row) ((row) * 7 + 4)
#define P_GX(row)  ((row) * 7 + 5)
#define P_GR(row)  ((row) * 7 + 6)

union UHp { uint32_t u; _Float16 s[2]; };
__device__ __forceinline__ uint32_t packh(float a, float b) {
    UHp x; x.s[0] = (_Float16)a; x.s[1] = (_Float16)b; return x.u;
}
__device__ __forceinline__ float dot2(uint32_t w, uint32_t a, float c) {
#if __has_builtin(__builtin_amdgcn_fdot2)
    typedef _Float16 h2 __attribute__((ext_vector_type(2)));
    union U { uint32_t u; h2 h; };
    U W, A; W.u = w; A.u = a;
    return __builtin_amdgcn_fdot2(W.h, A.h, c, false);
#else
    float d;
    asm("v_dot2_f32_f16 %0, %1, %2, %3" : "=v"(d) : "v"(w), "v"(a), "v"(c));
    return d;
#endif
}

// cheap transcendentals (r15-validated)
__device__ __forceinline__ float fexp2(float x) {
#if __has_builtin(__builtin_amdgcn_exp2f)
    return __builtin_amdgcn_exp2f(x);
#else
    return exp2f(x);
#endif
}
__device__ __forceinline__ float frcp(float x) {
#if __has_builtin(__builtin_amdgcn_rcpf)
    return __builtin_amdgcn_rcpf(x);
#else
    return 1.0f / x;
#endif
}
#define LOG2E 1.44269504f
__device__ __forceinline__ float fsig(float x)  { return frcp(1.0f + fexp2(-LOG2E * x)); }
__device__ __forceinline__ float ftanh(float x) { return 2.0f * frcp(1.0f + fexp2(-2.0f * LOG2E * x)) - 1.0f; }

#define D4(ACC, WP, V) \
    do { ACC = dot2((WP)[0], (V).x, ACC); ACC = dot2((WP)[1], (V).y, ACC); \
         ACC = dot2((WP)[2], (V).z, ACC); ACC = dot2((WP)[3], (V).w, ACC); } while (0)
#define D4X(A, X, WP, V) \
    do { A = dot2((WP)[0], (V).x, A); X = dot2((WP)[1], (V).y, X); \
         A = dot2((WP)[2], (V).z, A); X = dot2((WP)[3], (V).w, X); } while (0)

#define WAITGE(cache, ridx, need) \
    do { if ((cache) < (need)) { \
        volatile const int* _pf = (volatile const int*)&prog[(ridx)]; \
        int _v = *_pf; \
        while (_v < (need)) _v = *_pf; \
        (cache) = _v; } } while (0)

#define SIGNAL(ridx, val) \
    do { asm volatile("s_waitcnt lgkmcnt(0)" ::: "memory"); \
         *((volatile int*)&prog[(ridx)]) = (val); } while (0)

// Block = 2 batch rows as TWO independent single-row elastic pipelines.
// 896 threads = 14 waves (3.5/SIMD), grid 256 (1 block/CU -> guaranteed
// residency, unlike 2-blocks/CU schemes). Same total instruction count as the
// r15 champion (each wave does half the rows), but double the waves/SIMD to
// hide dot2-dependency + flag latency (r16 showed the stall is NOT ds_read).
// waves_per_eu(4,4) caps VGPR at 128 so 14 waves x <=128 <= 2048 pool.
// Role->wave map balances SIMDs (wv&3):
//  S0{L2Ar0,L1Ar0,VANr0,GRr0} S1{L2Br0,L1Br0,VANr1,GRr1}
//  S2{L2Ar1,L1Ar1,GXr0}       S3{L2Br1,L1Br1,GXr1}
__global__ __attribute__((amdgpu_flat_work_group_size(896, 896),
                          amdgpu_waves_per_eu(4, 4)))
void rnn_rs(
    const float* __restrict__ pix,
    const float* __restrict__ van_wi, const float* __restrict__ van_bi,
    const float* __restrict__ van_wh, const float* __restrict__ van_bh,
    const float* __restrict__ w1g, const float* __restrict__ b1g,
    const float* __restrict__ w2g, const float* __restrict__ b2g,
    const float* __restrict__ gwi, const float* __restrict__ gwh,
    const float* __restrict__ gb,
    const float* __restrict__ mw1, const float* __restrict__ mb1,
    const float* __restrict__ mw2, const float* __restrict__ mb2,
    const float* __restrict__ mw3, const float* __restrict__ mb3,
    const float* __restrict__ sf,
    float* __restrict__ out)
{
    const int tid  = threadIdx.x;
    const int wv   = tid >> 6;
    const int lane = tid & 63;
    const int r0   = 2 * blockIdx.x;

    // kind: 0=VAN 1=L1 2=L2 3=GX 4=GR ; row ; half (L1/L2 col-half)
    int kind, row, half = 0;
    switch (wv) {
        case 0:  kind = 2; row = 0; half = 0; break;
        case 1:  kind = 2; row = 0; half = 1; break;
        case 2:  kind = 2; row = 1; half = 0; break;
        case 3:  kind = 2; row = 1; half = 1; break;
        case 4:  kind = 1; row = 0; half = 0; break;
        case 5:  kind = 1; row = 0; half = 1; break;
        case 6:  kind = 1; row = 1; half = 0; break;
        case 7:  kind = 1; row = 1; half = 1; break;
        case 8:  kind = 0; row = 0; break;
        case 9:  kind = 0; row = 1; break;
        case 10: kind = 3; row = 0; break;
        case 11: kind = 3; row = 1; break;
        case 12: kind = 4; row = 0; break;
        default: kind = 4; row = 1; break;
    }

    __shared__ __align__(16) _Float16 xb [4][2][256];   // [slot][row]
    __shared__ __align__(16) _Float16 h0b[4][2][32];
    __shared__ __align__(16) _Float16 h1b[4][2][64];
    __shared__ __align__(16) _Float16 h2b[4][2][64];
    __shared__ __align__(16) _Float16 gxb[4][2][192];
    __shared__ __align__(16) _Float16 h3s[2][64];
    __shared__ __align__(16) _Float16 rh3s[2][64];
    __shared__ int prog[14];
    __shared__ float sHf[2][64];
    __shared__ float sT[2][64];
    __shared__ float sP[2][12];

    uint32_t wreg[128];
    float bz0 = 0.f, bz1 = 0.f, bz2 = 0.f;
    float st0 = 0.f;                     // lstm c / gru h3 (single row now)
    float4 pxA{}, pxB{};
    const float* pr = nullptr;

    // ---------------- per-role weight load (once) ----------------
    if (kind == 0) {                      // VAN row
        const int c = lane & 31, s = lane >> 5;
#pragma unroll
        for (int j = 0; j < 64; ++j)
            wreg[j] = packh(van_wi[(128 * s + 2 * j) * 32 + c],
                            van_wi[(128 * s + 2 * j + 1) * 32 + c]);
#pragma unroll
        for (int j = 0; j < 8; ++j)
            wreg[64 + j] = packh(van_wh[(16 * s + 2 * j) * 32 + c],
                                 van_wh[(16 * s + 2 * j + 1) * 32 + c]);
        bz0 = van_bi[c] + van_bh[c];
        pr = pix + (size_t)(r0 + row) * Tsz * Dsz;
#pragma unroll
        for (int t = 0; t < 2; ++t) {
            float4 p0 = *(const float4*)(pr + (size_t)t * Dsz + 4 * lane);
            uint32_t* x0 = (uint32_t*)xb[t][row];
            x0[2 * lane] = packh(p0.x, p0.y); x0[2 * lane + 1] = packh(p0.z, p0.w);
        }
        pxA = *(const float4*)(pr + 2 * (size_t)Dsz + 4 * lane);
        pxB = *(const float4*)(pr + 3 * (size_t)Dsz + 4 * lane);
    } else if (kind == 1) {               // L1 half,row
        const int p = half * 64 + lane;
        const int u = p >> 1, odd = p & 1;
        const int c0 = odd ? 128 + u : u, c1 = c0 + 64;
#pragma unroll
        for (int j = 0; j < 48; ++j)
            wreg[j] = packh(w1g[(2 * j) * 256 + c0], w1g[(2 * j + 1) * 256 + c0]);
#pragma unroll
        for (int j = 0; j < 48; ++j)
            wreg[48 + j] = packh(w1g[(2 * j) * 256 + c1], w1g[(2 * j + 1) * 256 + c1]);
        bz0 = b1g[c0]; bz1 = b1g[c1];
    } else if (kind == 2) {               // L2 half,row
        const int p = half * 64 + lane;
        const int u = p >> 1, odd = p & 1;
        const int c0 = odd ? 128 + u : u, c1 = c0 + 64;
#pragma unroll
        for (int j = 0; j < 64; ++j)
            wreg[j] = packh(w2g[(2 * j) * 256 + c0], w2g[(2 * j + 1) * 256 + c0]);
#pragma unroll
        for (int j = 0; j < 64; ++j)
            wreg[64 + j] = packh(w2g[(2 * j) * 256 + c1], w2g[(2 * j + 1) * 256 + c1]);
        bz0 = b2g[c0]; bz1 = b2g[c1];
    } else if (kind == 3) {               // GX row
#pragma unroll
        for (int j = 0; j < 32; ++j) {
            wreg[j]      = packh(gwi[(2 * j) * 192 + lane],       gwi[(2 * j + 1) * 192 + lane]);
            wreg[32 + j] = packh(gwi[(2 * j) * 192 + 64 + lane],  gwi[(2 * j + 1) * 192 + 64 + lane]);
            wreg[64 + j] = packh(gwi[(2 * j) * 192 + 128 + lane], gwi[(2 * j + 1) * 192 + 128 + lane]);
        }
        bz0 = gb[lane]; bz1 = gb[64 + lane]; bz2 = gb[128 + lane];
    } else {                              // GR row
#pragma unroll
        for (int j = 0; j < 32; ++j) {
            wreg[j]      = packh(gwh[(2 * j) * 192 + lane],       gwh[(2 * j + 1) * 192 + lane]);
            wreg[32 + j] = packh(gwh[(2 * j) * 192 + 64 + lane],  gwh[(2 * j + 1) * 192 + 64 + lane]);
            wreg[64 + j] = packh(gwh[(2 * j) * 192 + 128 + lane], gwh[(2 * j + 1) * 192 + 128 + lane]);
        }
    }

    for (int i = tid; i < 4 * 2 * 32;  i += 896) ((_Float16*)h0b)[i] = (_Float16)0.f;
    for (int i = tid; i < 4 * 2 * 64;  i += 896) ((_Float16*)h1b)[i] = (_Float16)0.f;
    for (int i = tid; i < 4 * 2 * 64;  i += 896) ((_Float16*)h2b)[i] = (_Float16)0.f;
    for (int i = tid; i < 4 * 2 * 192; i += 896) ((_Float16*)gxb)[i] = (_Float16)0.f;
    for (int i = tid; i < 2 * 64; i += 896) { ((_Float16*)h3s)[i] = (_Float16)0.f; ((_Float16*)rh3s)[i] = (_Float16)0.f; }
    if (tid < 14) prog[tid] = 0;
    __syncthreads();

    // ---------------- elastic pipelined recurrence (no barriers) ----------------
    if (kind == 0) {
        const int c = lane & 31, s = lane >> 5;
        int cA = 0, cB = 0;
        for (int t = 0; t < Tsz; ++t) {
            WAITGE(cA, P_L1A(row), t - 3);
            WAITGE(cB, P_L1B(row), t - 3);
            if (t + 2 < Tsz) {
                uint32_t* x0 = (uint32_t*)xb[(t + 2) & 3][row];
                x0[2 * lane] = packh(pxA.x, pxA.y); x0[2 * lane + 1] = packh(pxA.z, pxA.w);
            }
            pxA = pxB;
            if (t + 4 < Tsz)
                pxB = *(const float4*)(pr + (size_t)(t + 4) * Dsz + 4 * lane);
            {
                const uint4* xq = ((const uint4*)xb[t & 3][row]) + 16 * s;
                const uint4* hq = ((const uint4*)h0b[(t - 1) & 3][row]) + 2 * s;
                float a0 = 0.f, a1 = 0.f;
#pragma unroll
                for (int q = 0; q < 16; q += 2) {
                    uint4 v0 = xq[q], v1 = xq[q + 1];
                    D4(a0, &wreg[4 * q], v0);
                    D4(a1, &wreg[4 * q + 4], v1);
                }
                {
                    uint4 v0 = hq[0], v1 = hq[1];
                    D4(a0, &wreg[64], v0);
                    D4(a1, &wreg[68], v1);
                }
                float acc = a0 + a1;
                acc += __shfl_xor(acc, 32);
                if (s == 0) h0b[t & 3][row][c] = (_Float16)fmaxf(acc + bz0, 0.f);
            }
            SIGNAL(P_VAN(row), t + 1);
        }
    } else if (kind == 1) {
        const int self = half ? P_L1B(row) : P_L1A(row);
        const int prt  = half ? P_L1A(row) : P_L1B(row);
        const int p = half * 64 + lane;
        const int u = p >> 1, odd = p & 1;
        int cv = 0, cp = 0, c2a = 0, c2b = 0;
        for (int t = 0; t < Tsz; ++t) {
            WAITGE(cv, P_VAN(row), t + 1);
            WAITGE(cp, prt, t);
            WAITGE(c2a, P_L2A(row), t - 3);
            WAITGE(c2b, P_L2B(row), t - 3);
            {
                const uint4* aq = (const uint4*)h0b[t & 3][row];        // k 0..31
                const uint4* bq = (const uint4*)h1b[(t - 1) & 3][row];  // k 32..95
                float a0 = bz0, a1 = bz1, x0 = 0.f, x1 = 0.f;
#pragma unroll
                for (int q = 0; q < 4; ++q) {
                    uint4 v = aq[q];
                    D4X(a0, x0, &wreg[4 * q], v);
                    D4X(a1, x1, &wreg[48 + 4 * q], v);
                }
#pragma unroll
                for (int q = 0; q < 8; ++q) {
                    uint4 v = bq[q];
                    D4X(a0, x0, &wreg[16 + 4 * q], v);
                    D4X(a1, x1, &wreg[64 + 4 * q], v);
                }
                float g0 = a0 + x0, g1 = a1 + x1;
                float ain = odd ? g0 + 1.f : g0;
                float bin = odd ? g1 : g1 + g1;
                float s0 = fsig(ain);
                float s1 = fsig(bin);
                float send = s0 * (2.f * s1 - 1.f);
                float prx = __shfl_xor(send, 1);
                st0 = s0 * st0 + prx;            // valid on odd lanes
                float tc = ftanh(st0);
                if (odd) h1b[t & 3][row][u] = (_Float16)(s1 * tc);
            }
            SIGNAL(self, t + 1);
        }
    } else if (kind == 2) {
        const int self = half ? P_L2B(row) : P_L2A(row);
        const int prt  = half ? P_L2A(row) : P_L2B(row);
        const int p = half * 64 + lane;
        const int u = p >> 1, odd = p & 1;
        int c1a = 0, c1b = 0, cp = 0, cg = 0;
        for (int t = 0; t < Tsz; ++t) {
            WAITGE(c1a, P_L1A(row), t + 1);
            WAITGE(c1b, P_L1B(row), t + 1);
            WAITGE(cp, prt, t);
            WAITGE(cg, P_GX(row), t - 3);
            {
                const uint4* aq = (const uint4*)h1b[t & 3][row];        // k 0..63
                const uint4* bq = (const uint4*)h2b[(t - 1) & 3][row];  // k 64..127
                float a0 = bz0, a1 = bz1, x0 = 0.f, x1 = 0.f;
#pragma unroll
                for (int q = 0; q < 8; ++q) {
                    uint4 v = aq[q];
                    D4X(a0, x0, &wreg[4 * q], v);
                    D4X(a1, x1, &wreg[64 + 4 * q], v);
                }
#pragma unroll
                for (int q = 0; q < 8; ++q) {
                    uint4 v = bq[q];
                    D4X(a0, x0, &wreg[32 + 4 * q], v);
                    D4X(a1, x1, &wreg[96 + 4 * q], v);
                }
                float g0 = a0 + x0, g1 = a1 + x1;
                float ain = odd ? g0 + 1.f : g0;
                float bin = odd ? g1 : g1 + g1;
                float s0 = fsig(ain);
                float s1 = fsig(bin);
                float send = s0 * (2.f * s1 - 1.f);
                float prx = __shfl_xor(send, 1);
                st0 = s0 * st0 + prx;
                float tc = ftanh(st0);
                if (odd) h2b[t & 3][row][u] = (_Float16)(s1 * tc);
            }
            SIGNAL(self, t + 1);
        }
    } else if (kind == 3) {
        int c2a = 0, c2b = 0, gc = 0;
        for (int t = 0; t < Tsz; ++t) {
            WAITGE(c2a, P_L2A(row), t + 1);
            WAITGE(c2b, P_L2B(row), t + 1);
            WAITGE(gc, P_GR(row), t - 3);
            {
                const uint4* hq = (const uint4*)h2b[t & 3][row];
                float az = bz0, ar = bz1, aa = bz2;
#pragma unroll
                for (int q = 0; q < 8; ++q) {
                    uint4 v = hq[q];
                    D4(az, &wreg[4 * q], v);
                    D4(ar, &wreg[32 + 4 * q], v);
                    D4(aa, &wreg[64 + 4 * q], v);
                }
                gxb[t & 3][row][lane]       = (_Float16)az;
                gxb[t & 3][row][64 + lane]  = (_Float16)ar;
                gxb[t & 3][row][128 + lane] = (_Float16)aa;
            }
            SIGNAL(P_GX(row), t + 1);
        }
    } else {   // GR row
        int cg = 0;
        for (int t = 0; t < Tsz; ++t) {
            WAITGE(cg, P_GX(row), t + 1);
            const uint4* hq = (const uint4*)h3s[row];
            float az = (float)gxb[t & 3][row][lane];
            float ar = (float)gxb[t & 3][row][64 + lane];
#pragma unroll
            for (int q = 0; q < 8; ++q) {
                uint4 v = hq[q];
                D4(az, &wreg[4 * q], v);
                D4(ar, &wreg[32 + 4 * q], v);
            }
            float z = fsig(az);
            rh3s[row][lane] = (_Float16)(fsig(ar) * st0);
            float ga = (float)gxb[t & 3][row][128 + lane];
            asm volatile("s_waitcnt lgkmcnt(0)" ::: "memory");   // wave-sync LDS
            const uint4* rq = (const uint4*)rh3s[row];
            float aa = ga, ab = 0.f;
#pragma unroll
            for (int q = 0; q < 8; ++q) {
                uint4 v = rq[q];
                if (q & 1) { D4(ab, &wreg[64 + 4 * q], v); }
                else       { D4(aa, &wreg[64 + 4 * q], v); }
            }
            float av = ftanh(aa + ab);
            st0 = (1.f - z) * st0 + z * av;
            h3s[row][lane] = (_Float16)st0;
            SIGNAL(P_GR(row), t + 1);
        }
    }

    if (wv == 12) sHf[0][lane] = st0;
    if (wv == 13) sHf[1][lane] = st0;
    __syncthreads();

    // ---------------- MLP head (2 rows) ----------------
    if (tid < 64) {
        const int r = tid >> 5, c = tid & 31;
        float acc = mb1[c];
#pragma unroll
        for (int kk = 0; kk < 64; ++kk) acc = fmaf(sHf[r][kk], mw1[kk * 32 + c], acc);
        sT[r][c] = fmaxf(acc, 0.f);
    }
    __syncthreads();
    if (tid < 64) {
        const int r = tid >> 5, c = tid & 31;
        float acc = mb2[c];
#pragma unroll
        for (int kk = 0; kk < 32; ++kk) acc = fmaf(sT[r][kk], mw2[kk * 32 + c], acc);
        sT[r][32 + c] = fmaxf(acc, 0.f);
    }
    __syncthreads();
    if (tid < 24) {
        const int r = tid / 12, c = tid - 12 * r;
        float acc = mb3[c];
#pragma unroll
        for (int kk = 0; kk < 32; ++kk) acc = fmaf(sT[r][32 + kk], mw3[kk * 12 + c], acc);
        sP[r][c] = acc;
    }
    __syncthreads();
    if (tid < 2) {
        float acc = 0.f;
#pragma unroll
        for (int kk = 0; kk < 12; ++kk) acc = fmaf(sP[tid][kk], sf[kk], acc);
        out[24 + r0 + tid] = acc;
    }
    if (blockIdx.x == 0 && tid < 12) {
        out[tid] = sf[tid];
        out[12 + tid] = 1.0f;
    }
}

extern "C" void kernel_launch(void* const* d_in, const int* in_sizes, int n_in,
                              void* d_out, int out_size, void* d_ws, size_t ws_size,
                              hipStream_t stream) {
    (void)in_sizes; (void)n_in; (void)d_ws; (void)ws_size; (void)out_size;
    const float* pix    = (const float*)d_in[0];
    const float* van_wi = (const float*)d_in[1];
    const float* van_bi = (const float*)d_in[2];
    const float* van_wh = (const float*)d_in[3];
    const float* van_bh = (const float*)d_in[4];
    const float* w1     = (const float*)d_in[5];
    const float* b1     = (const float*)d_in[6];
    const float* w2     = (const float*)d_in[7];
    const float* b2     = (const float*)d_in[8];
    const float* gwi    = (const float*)d_in[9];
    const float* gwh    = (const float*)d_in[10];
    const float* gb     = (const float*)d_in[11];
    const float* mw1    = (const float*)d_in[12];
    const float* mb1    = (const float*)d_in[13];
    const float* mw2    = (const float*)d_in[14];
    const float* mb2    = (const float*)d_in[15];
    const float* mw3    = (const float*)d_in[16];
    const float* mb3    = (const float*)d_in[17];
    const float* sf     = (const float*)d_in[18];
    float* out = (float*)d_out;

    rnn_rs<<<256, 896, 0, stream>>>(
        pix, van_wi, van_bi, van_wh, van_bh,
        w1, b1, w2, b2, gwi, gwh, gb,
        mw1, mb1, mw2, mb2, mw3, mb3, sf, out);
}

// Round 18
// 656.753 us; speedup vs baseline: 3.0249x; 3.0249x over previous
//
#include <hip/hip_runtime.h>
#include <stdint.h>

#define Tsz 512
#define Dsz 256

// role ids (prog[] index)
#define R_VAN 0
#define R_L1A 1
#define R_L1B 2
#define R_L2A 3
#define R_L2B 4
#define R_GX  5
#define R_GR0 6
#define R_GR1 7

union UHp { uint32_t u; _Float16 s[2]; };
__device__ __forceinline__ uint32_t packh(float a, float b) {
    UHp x; x.s[0] = (_Float16)a; x.s[1] = (_Float16)b; return x.u;
}
__device__ __forceinline__ float dot2(uint32_t w, uint32_t a, float c) {
#if __has_builtin(__builtin_amdgcn_fdot2)
    typedef _Float16 h2 __attribute__((ext_vector_type(2)));
    union U { uint32_t u; h2 h; };
    U W, A; W.u = w; A.u = a;
    return __builtin_amdgcn_fdot2(W.h, A.h, c, false);
#else
    float d;
    asm("v_dot2_f32_f16 %0, %1, %2, %3" : "=v"(d) : "v"(w), "v"(a), "v"(c));
    return d;
#endif
}

// cheap transcendentals (r15-validated: -16%, absmax unchanged)
__device__ __forceinline__ float fexp2(float x) {
#if __has_builtin(__builtin_amdgcn_exp2f)
    return __builtin_amdgcn_exp2f(x);
#else
    return exp2f(x);
#endif
}
__device__ __forceinline__ float frcp(float x) {
#if __has_builtin(__builtin_amdgcn_rcpf)
    return __builtin_amdgcn_rcpf(x);
#else
    return 1.0f / x;
#endif
}
#define LOG2E 1.44269504f
__device__ __forceinline__ float fsig(float x)  { return frcp(1.0f + fexp2(-LOG2E * x)); }
__device__ __forceinline__ float ftanh(float x) { return 2.0f * frcp(1.0f + fexp2(-2.0f * LOG2E * x)) - 1.0f; }

#define D4(ACC, WP, V) \
    do { ACC = dot2((WP)[0], (V).x, ACC); ACC = dot2((WP)[1], (V).y, ACC); \
         ACC = dot2((WP)[2], (V).z, ACC); ACC = dot2((WP)[3], (V).w, ACC); } while (0)
#define D4X(A, X, WP, V) \
    do { A = dot2((WP)[0], (V).x, A); X = dot2((WP)[1], (V).y, X); \
         A = dot2((WP)[2], (V).z, A); X = dot2((WP)[3], (V).w, X); } while (0)

// cached flag wait (monotonic counters; re-read only when cache insufficient)
#define WAITGE(cache, ridx, need) \
    do { if ((cache) < (need)) { \
        volatile const int* _pf = (volatile const int*)&prog[(ridx)]; \
        int _v = *_pf; \
        while (_v < (need)) _v = *_pf; \
        (cache) = _v; } } while (0)

#define SIGNAL(ridx, val) \
    do { asm volatile("s_waitcnt lgkmcnt(0)" ::: "memory"); \
         *((volatile int*)&prog[(ridx)]) = (val); } while (0)

// r15 CHAMPION restored byte-identical (654 us validated).
// Design ledger (17 rounds):
//  - elastic flag pipeline, 8 waves, 2 rows/block, grid 256 (1 block/CU)
//  - weights in registers (AGPR-backed is fine: VALU reads AGPR directly)
//  - cheap rcp/exp transcendentals + branchless gates (r15: -16%)
//  - DO NOT raise waves/SIMD: >2-3 waves/EU shrinks the register grant and
//    spills weights to scratch (r17: waves_per_eu(4,4) -> 64 VGPR, 22MB
//    scratch writes, 3x regression). DO NOT add prefetch (r16: flat).
__global__ __attribute__((amdgpu_flat_work_group_size(512, 512),
                          amdgpu_waves_per_eu(2, 2)))
void rnn_flag2(
    const float* __restrict__ pix,
    const float* __restrict__ van_wi, const float* __restrict__ van_bi,
    const float* __restrict__ van_wh, const float* __restrict__ van_bh,
    const float* __restrict__ w1g, const float* __restrict__ b1g,
    const float* __restrict__ w2g, const float* __restrict__ b2g,
    const float* __restrict__ gwi, const float* __restrict__ gwh,
    const float* __restrict__ gb,
    const float* __restrict__ mw1, const float* __restrict__ mb1,
    const float* __restrict__ mw2, const float* __restrict__ mb2,
    const float* __restrict__ mw3, const float* __restrict__ mb3,
    const float* __restrict__ sf,
    float* __restrict__ out)
{
    const int tid  = threadIdx.x;
    const int wv   = tid >> 6;
    const int lane = tid & 63;
    const int r0   = 2 * blockIdx.x;

    int role;
    switch (wv) {
        case 0: role = R_L2A; break;
        case 1: role = R_L2B; break;
        case 2: role = R_VAN; break;
        case 3: role = R_GX;  break;
        case 4: role = R_GR0; break;
        case 5: role = R_GR1; break;
        case 6: role = R_L1A; break;
        default: role = R_L1B; break;
    }

    __shared__ __align__(16) _Float16 xb [4][2][256];   // [slot][row]
    __shared__ __align__(16) _Float16 h0b[4][2][32];
    __shared__ __align__(16) _Float16 h1b[4][2][64];
    __shared__ __align__(16) _Float16 h2b[4][2][64];
    __shared__ __align__(16) _Float16 gxb[4][2][192];
    __shared__ __align__(16) _Float16 h3s[2][64];       // gru-wave private per row
    __shared__ __align__(16) _Float16 rh3s[2][64];
    __shared__ int prog[8];
    __shared__ float sHf[2][64];
    __shared__ float sT[2][64];
    __shared__ float sP[2][12];

    uint32_t wreg[128];
    float bz0 = 0.f, bz1 = 0.f, bz2 = 0.f;
    float st0 = 0.f, st1 = 0.f;          // lstm c (rows 0/1) or gru h3 (own row)
    float4 pxA0{}, pxB0{}, pxA1{}, pxB1{};
    const float* pr0 = nullptr; const float* pr1 = nullptr;

    // ---------------- per-role weight load (once) ----------------
    if (role == R_VAN) {
        const int c = lane & 31, s = lane >> 5;
#pragma unroll
        for (int j = 0; j < 64; ++j)
            wreg[j] = packh(van_wi[(128 * s + 2 * j) * 32 + c],
                            van_wi[(128 * s + 2 * j + 1) * 32 + c]);
#pragma unroll
        for (int j = 0; j < 8; ++j)
            wreg[64 + j] = packh(van_wh[(16 * s + 2 * j) * 32 + c],
                                 van_wh[(16 * s + 2 * j + 1) * 32 + c]);
        bz0 = van_bi[c] + van_bh[c];
        pr0 = pix + (size_t)r0 * Tsz * Dsz;
        pr1 = pr0 + (size_t)Tsz * Dsz;
        // prologue: x(0),x(1) -> slots 0,1; pxA=x(2), pxB=x(3)
#pragma unroll
        for (int t = 0; t < 2; ++t) {
            float4 p0 = *(const float4*)(pr0 + (size_t)t * Dsz + 4 * lane);
            float4 p1 = *(const float4*)(pr1 + (size_t)t * Dsz + 4 * lane);
            uint32_t* x0 = (uint32_t*)xb[t][0];
            uint32_t* x1 = (uint32_t*)xb[t][1];
            x0[2 * lane] = packh(p0.x, p0.y); x0[2 * lane + 1] = packh(p0.z, p0.w);
            x1[2 * lane] = packh(p1.x, p1.y); x1[2 * lane + 1] = packh(p1.z, p1.w);
        }
        pxA0 = *(const float4*)(pr0 + 2 * (size_t)Dsz + 4 * lane);
        pxA1 = *(const float4*)(pr1 + 2 * (size_t)Dsz + 4 * lane);
        pxB0 = *(const float4*)(pr0 + 3 * (size_t)Dsz + 4 * lane);
        pxB1 = *(const float4*)(pr1 + 3 * (size_t)Dsz + 4 * lane);
    } else if (role == R_L1A || role == R_L1B) {
        const int p = (role == R_L1A ? 0 : 64) + lane;
        const int u = p >> 1, odd = p & 1;
        const int c0 = odd ? 128 + u : u, c1 = c0 + 64;
#pragma unroll
        for (int j = 0; j < 48; ++j)
            wreg[j] = packh(w1g[(2 * j) * 256 + c0], w1g[(2 * j + 1) * 256 + c0]);
#pragma unroll
        for (int j = 0; j < 48; ++j)
            wreg[48 + j] = packh(w1g[(2 * j) * 256 + c1], w1g[(2 * j + 1) * 256 + c1]);
        bz0 = b1g[c0]; bz1 = b1g[c1];
    } else if (role == R_L2A || role == R_L2B) {
        const int p = (role == R_L2A ? 0 : 64) + lane;
        const int u = p >> 1, odd = p & 1;
        const int c0 = odd ? 128 + u : u, c1 = c0 + 64;
#pragma unroll
        for (int j = 0; j < 64; ++j)
            wreg[j] = packh(w2g[(2 * j) * 256 + c0], w2g[(2 * j + 1) * 256 + c0]);
#pragma unroll
        for (int j = 0; j < 64; ++j)
            wreg[64 + j] = packh(w2g[(2 * j) * 256 + c1], w2g[(2 * j + 1) * 256 + c1]);
        bz0 = b2g[c0]; bz1 = b2g[c1];
    } else if (role == R_GX) {
#pragma unroll
        for (int j = 0; j < 32; ++j) {
            wreg[j]      = packh(gwi[(2 * j) * 192 + lane],       gwi[(2 * j + 1) * 192 + lane]);
            wreg[32 + j] = packh(gwi[(2 * j) * 192 + 64 + lane],  gwi[(2 * j + 1) * 192 + 64 + lane]);
            wreg[64 + j] = packh(gwi[(2 * j) * 192 + 128 + lane], gwi[(2 * j + 1) * 192 + 128 + lane]);
        }
        bz0 = gb[lane]; bz1 = gb[64 + lane]; bz2 = gb[128 + lane];
    } else {   // R_GR0 / R_GR1
#pragma unroll
        for (int j = 0; j < 32; ++j) {
            wreg[j]      = packh(gwh[(2 * j) * 192 + lane],       gwh[(2 * j + 1) * 192 + lane]);
            wreg[32 + j] = packh(gwh[(2 * j) * 192 + 64 + lane],  gwh[(2 * j + 1) * 192 + 64 + lane]);
            wreg[64 + j] = packh(gwh[(2 * j) * 192 + 128 + lane], gwh[(2 * j + 1) * 192 + 128 + lane]);
        }
    }

    for (int i = tid; i < 4 * 2 * 32;  i += 512) ((_Float16*)h0b)[i] = (_Float16)0.f;
    for (int i = tid; i < 4 * 2 * 64;  i += 512) ((_Float16*)h1b)[i] = (_Float16)0.f;
    for (int i = tid; i < 4 * 2 * 64;  i += 512) ((_Float16*)h2b)[i] = (_Float16)0.f;
    for (int i = tid; i < 4 * 2 * 192; i += 512) ((_Float16*)gxb)[i] = (_Float16)0.f;
    for (int i = tid; i < 2 * 64; i += 512) { ((_Float16*)h3s)[i] = (_Float16)0.f; ((_Float16*)rh3s)[i] = (_Float16)0.f; }
    if (tid < 8) prog[tid] = 0;
    __syncthreads();

    // ---------------- elastic pipelined recurrence (no barriers) ----------------
    if (role == R_VAN) {
        const int c = lane & 31, s = lane >> 5;
        int cA = 0, cB = 0;
        for (int t = 0; t < Tsz; ++t) {
            WAITGE(cA, R_L1A, t - 3);
            WAITGE(cB, R_L1B, t - 3);
            if (t + 2 < Tsz) {
                uint32_t* x0 = (uint32_t*)xb[(t + 2) & 3][0];
                uint32_t* x1 = (uint32_t*)xb[(t + 2) & 3][1];
                x0[2 * lane] = packh(pxA0.x, pxA0.y); x0[2 * lane + 1] = packh(pxA0.z, pxA0.w);
                x1[2 * lane] = packh(pxA1.x, pxA1.y); x1[2 * lane + 1] = packh(pxA1.z, pxA1.w);
            }
            pxA0 = pxB0; pxA1 = pxB1;
            if (t + 4 < Tsz) {
                pxB0 = *(const float4*)(pr0 + (size_t)(t + 4) * Dsz + 4 * lane);
                pxB1 = *(const float4*)(pr1 + (size_t)(t + 4) * Dsz + 4 * lane);
            }
#pragma unroll
            for (int r = 0; r < 2; ++r) {
                const uint4* xq = ((const uint4*)xb[t & 3][r]) + 16 * s;
                const uint4* hq = ((const uint4*)h0b[(t - 1) & 3][r]) + 2 * s;
                float a0 = 0.f, a1 = 0.f;
#pragma unroll
                for (int q = 0; q < 16; q += 2) {
                    uint4 v0 = xq[q], v1 = xq[q + 1];
                    D4(a0, &wreg[4 * q], v0);
                    D4(a1, &wreg[4 * q + 4], v1);
                }
                {
                    uint4 v0 = hq[0], v1 = hq[1];
                    D4(a0, &wreg[64], v0);
                    D4(a1, &wreg[68], v1);
                }
                float acc = a0 + a1;
                acc += __shfl_xor(acc, 32);
                if (s == 0) h0b[t & 3][r][c] = (_Float16)fmaxf(acc + bz0, 0.f);
            }
            SIGNAL(R_VAN, t + 1);
        }
    } else if (role == R_L1A || role == R_L1B) {
        const int prt = (role == R_L1A) ? R_L1B : R_L1A;
        const int p = (role == R_L1A ? 0 : 64) + lane;
        const int u = p >> 1, odd = p & 1;
        int cv = 0, cp = 0, c2a = 0, c2b = 0;
        for (int t = 0; t < Tsz; ++t) {
            WAITGE(cv, R_VAN, t + 1);          // h0(t) ready
            WAITGE(cp, prt, t);                // partner's h1(t-1) half ready
            WAITGE(c2a, R_L2A, t - 3);         // h1(t-4) consumed before overwrite
            WAITGE(c2b, R_L2B, t - 3);
#pragma unroll
            for (int r = 0; r < 2; ++r) {
                const uint4* aq = (const uint4*)h0b[t & 3][r];        // k 0..31
                const uint4* bq = (const uint4*)h1b[(t - 1) & 3][r];  // k 32..95
                float a0 = bz0, a1 = bz1, x0 = 0.f, x1 = 0.f;
#pragma unroll
                for (int q = 0; q < 4; ++q) {
                    uint4 v = aq[q];
                    D4X(a0, x0, &wreg[4 * q], v);
                    D4X(a1, x1, &wreg[48 + 4 * q], v);
                }
#pragma unroll
                for (int q = 0; q < 8; ++q) {
                    uint4 v = bq[q];
                    D4X(a0, x0, &wreg[16 + 4 * q], v);
                    D4X(a1, x1, &wreg[64 + 4 * q], v);
                }
                float g0 = a0 + x0, g1 = a1 + x1;
                // branchless gates: even lane holds (i,g) cols, odd (f,o)
                float ain = odd ? g0 + 1.f : g0;       // sig arg: f+1 | i
                float bin = odd ? g1 : g1 + g1;        // sig arg: o | 2g
                float s0 = fsig(ain);
                float s1 = fsig(bin);
                float send = s0 * (2.f * s1 - 1.f);    // even: sig(i)*tanh(g)
                float prx = __shfl_xor(send, 1);
                float cs = r ? st1 : st0;
                cs = s0 * cs + prx;                    // odd: sig(f+1)*c + i*g
                if (r) st1 = cs; else st0 = cs;
                float tc = ftanh(cs);
                if (odd) h1b[t & 3][r][u] = (_Float16)(s1 * tc);
            }
            SIGNAL(role, t + 1);
        }
    } else if (role == R_L2A || role == R_L2B) {
        const int prt = (role == R_L2A) ? R_L2B : R_L2A;
        const int p = (role == R_L2A ? 0 : 64) + lane;
        const int u = p >> 1, odd = p & 1;
        int c1a = 0, c1b = 0, cp = 0, cg = 0;
        for (int t = 0; t < Tsz; ++t) {
            WAITGE(c1a, R_L1A, t + 1);         // h1(t) ready (both halves)
            WAITGE(c1b, R_L1B, t + 1);
            WAITGE(cp, prt, t);                // partner's h2(t-1) half
            WAITGE(cg, R_GX, t - 3);           // h2(t-4) consumed before overwrite
#pragma unroll
            for (int r = 0; r < 2; ++r) {
                const uint4* aq = (const uint4*)h1b[t & 3][r];        // k 0..63
                const uint4* bq = (const uint4*)h2b[(t - 1) & 3][r];  // k 64..127
                float a0 = bz0, a1 = bz1, x0 = 0.f, x1 = 0.f;
#pragma unroll
                for (int q = 0; q < 8; ++q) {
                    uint4 v = aq[q];
                    D4X(a0, x0, &wreg[4 * q], v);
                    D4X(a1, x1, &wreg[64 + 4 * q], v);
                }
#pragma unroll
                for (int q = 0; q < 8; ++q) {
                    uint4 v = bq[q];
                    D4X(a0, x0, &wreg[32 + 4 * q], v);
                    D4X(a1, x1, &wreg[96 + 4 * q], v);
                }
                float g0 = a0 + x0, g1 = a1 + x1;
                float ain = odd ? g0 + 1.f : g0;
                float bin = odd ? g1 : g1 + g1;
                float s0 = fsig(ain);
                float s1 = fsig(bin);
                float send = s0 * (2.f * s1 - 1.f);
                float prx = __shfl_xor(send, 1);
                float cs = r ? st1 : st0;
                cs = s0 * cs + prx;
                if (r) st1 = cs; else st0 = cs;
                float tc = ftanh(cs);
                if (odd) h2b[t & 3][r][u] = (_Float16)(s1 * tc);
            }
            SIGNAL(role, t + 1);
        }
    } else if (role == R_GX) {
        int c2a = 0, c2b = 0, g0c = 0, g1c = 0;
        for (int t = 0; t < Tsz; ++t) {
            WAITGE(c2a, R_L2A, t + 1);         // h2(t) ready
            WAITGE(c2b, R_L2B, t + 1);
            WAITGE(g0c, R_GR0, t - 3);         // gxb(t-4) consumed before overwrite
            WAITGE(g1c, R_GR1, t - 3);
#pragma unroll
            for (int r = 0; r < 2; ++r) {
                const uint4* hq = (const uint4*)h2b[t & 3][r];
                float az = bz0, ar = bz1, aa = bz2;
#pragma unroll
                for (int q = 0; q < 8; ++q) {
                    uint4 v = hq[q];
                    D4(az, &wreg[4 * q], v);
                    D4(ar, &wreg[32 + 4 * q], v);
                    D4(aa, &wreg[64 + 4 * q], v);
                }
                gxb[t & 3][r][lane]       = (_Float16)az;
                gxb[t & 3][r][64 + lane]  = (_Float16)ar;
                gxb[t & 3][r][128 + lane] = (_Float16)aa;
            }
            SIGNAL(R_GX, t + 1);
        }
    } else {   // R_GR0 / R_GR1
        const int r = (role == R_GR0) ? 0 : 1;
        int cg = 0;
        for (int t = 0; t < Tsz; ++t) {
            WAITGE(cg, R_GX, t + 1);           // gx(t) ready
            const uint4* hq = (const uint4*)h3s[r];
            float az = (float)gxb[t & 3][r][lane];
            float ar = (float)gxb[t & 3][r][64 + lane];
#pragma unroll
            for (int q = 0; q < 8; ++q) {
                uint4 v = hq[q];
                D4(az, &wreg[4 * q], v);
                D4(ar, &wreg[32 + 4 * q], v);
            }
            float z = fsig(az);
            rh3s[r][lane] = (_Float16)(fsig(ar) * st0);
            float ga = (float)gxb[t & 3][r][128 + lane];
            asm volatile("s_waitcnt lgkmcnt(0)" ::: "memory");   // wave-sync LDS
            const uint4* rq = (const uint4*)rh3s[r];
            float aa = ga, ab = 0.f;
#pragma unroll
            for (int q = 0; q < 8; ++q) {
                uint4 v = rq[q];
                if (q & 1) { D4(ab, &wreg[64 + 4 * q], v); }
                else       { D4(aa, &wreg[64 + 4 * q], v); }
            }
            float av = ftanh(aa + ab);
            st0 = (1.f - z) * st0 + z * av;
            h3s[r][lane] = (_Float16)st0;
            SIGNAL(role, t + 1);
        }
    }

    if (role == R_GR0) sHf[0][lane] = st0;
    if (role == R_GR1) sHf[1][lane] = st0;
    __syncthreads();

    // ---------------- MLP head (2 rows) ----------------
    if (tid < 64) {
        const int r = tid >> 5, c = tid & 31;
        float acc = mb1[c];
#pragma unroll
        for (int kk = 0; kk < 64; ++kk) acc = fmaf(sHf[r][kk], mw1[kk * 32 + c], acc);
        sT[r][c] = fmaxf(acc, 0.f);
    }
    __syncthreads();
    if (tid < 64) {
        const int r = tid >> 5, c = tid & 31;
        float acc = mb2[c];
#pragma unroll
        for (int kk = 0; kk < 32; ++kk) acc = fmaf(sT[r][kk], mw2[kk * 32 + c], acc);
        sT[r][32 + c] = fmaxf(acc, 0.f);
    }
    __syncthreads();
    if (tid < 24) {
        const int r = tid / 12, c = tid - 12 * r;
        float acc = mb3[c];
#pragma unroll
        for (int kk = 0; kk < 32; ++kk) acc = fmaf(sT[r][32 + kk], mw3[kk * 12 + c], acc);
        sP[r][c] = acc;
    }
    __syncthreads();
    if (tid < 2) {
        float acc = 0.f;
#pragma unroll
        for (int kk = 0; kk < 12; ++kk) acc = fmaf(sP[tid][kk], sf[kk], acc);
        out[24 + r0 + tid] = acc;
    }
    if (blockIdx.x == 0 && tid < 12) {
        out[tid] = sf[tid];
        out[12 + tid] = 1.0f;
    }
}

extern "C" void kernel_launch(void* const* d_in, const int* in_sizes, int n_in,
                              void* d_out, int out_size, void* d_ws, size_t ws_size,
                              hipStream_t stream) {
    (void)in_sizes; (void)n_in; (void)d_ws; (void)ws_size; (void)out_size;
    const float* pix    = (const float*)d_in[0];
    const float* van_wi = (const float*)d_in[1];
    const float* van_bi = (const float*)d_in[2];
    const float* van_wh = (const float*)d_in[3];
    const float* van_bh = (const float*)d_in[4];
    const float* w1     = (const float*)d_in[5];
    const float* b1     = (const float*)d_in[6];
    const float* w2     = (const float*)d_in[7];
    const float* b2     = (const float*)d_in[8];
    const float* gwi    = (const float*)d_in[9];
    const float* gwh    = (const float*)d_in[10];
    const float* gb     = (const float*)d_in[11];
    const float* mw1    = (const float*)d_in[12];
    const float* mb1    = (const float*)d_in[13];
    const float* mw2    = (const float*)d_in[14];
    const float* mb2    = (const float*)d_in[15];
    const float* mw3    = (const float*)d_in[16];
    const float* mb3    = (const float*)d_in[17];
    const float* sf     = (const float*)d_in[18];
    float* out = (float*)d_out;

    rnn_flag2<<<256, 512, 0, stream>>>(
        pix, van_wi, van_bi, van_wh, van_bh,
        w1, b1, w2, b2, gwi, gwh, gb,
        mw1, mb1, mw2, mb2, mw3, mb3, sf, out);
}